// Round 1
// baseline (15073.421 us; speedup 1.0000x reference)
//
#include <hip/hip_runtime.h>
#include <math.h>

#define S_LEN 4096
#define HDIRC 256
#define NTAG 10
#define START_TAG 8
#define STOP_TAG 9
#define NEGV -10000.0f

// -------- workspace layout (float units) --------
#define XW_OFF 0UL
#define XW_SZ  (2UL * S_LEN * 1024)          // xw[dir][t][1024]
#define HS_OFF (XW_OFF + XW_SZ)
#define HS_SZ  (2UL * S_LEN * 256)           // hs[dir][t][256] (dir1 indexed by backward step)
#define WT_OFF (HS_OFF + HS_SZ)
#define WT_SZ  (2UL * 256 * 1024)            // WihT[dir][k][r]
#define FE_OFF (WT_OFF + WT_SZ)
#define FE_SZ  ((size_t)S_LEN * NTAG)        // feats[t][tag]
#define CNT_OFF (FE_OFF + FE_SZ)
#define CNT_SZ (2UL * S_LEN)                 // arrive counters per dir per step

// ---------------- Wih transpose: [1024][256] -> [256][1024] ----------------
__global__ void transpose_wih(const float* __restrict__ wf,
                              const float* __restrict__ wb,
                              float* __restrict__ wT) {
    __shared__ float tile[32][33];
    const float* src = blockIdx.z ? wb : wf;
    float* dst = wT + (size_t)blockIdx.z * 256 * 1024;
    int x = blockIdx.x * 32 + threadIdx.x;   // k  (0..255)
    int y = blockIdx.y * 32 + threadIdx.y;   // r  (0..1023)
    tile[threadIdx.y][threadIdx.x] = src[y * 256 + x];
    __syncthreads();
    int ko = blockIdx.x * 32 + threadIdx.y;
    int ro = blockIdx.y * 32 + threadIdx.x;
    dst[(size_t)ko * 1024 + ro] = tile[threadIdx.x][threadIdx.y];
}

// ---------------- xW = emb[sent] @ Wih^T + (bih+bhh) ----------------
// grid (S/16, 2), block 256. Thread owns 4 consecutive rows r=4*tid..4*tid+3,
// 16 timesteps per block. Wih read via transposed copy -> coalesced float4.
__global__ __launch_bounds__(256) void xw_gemm(
    const int* __restrict__ sent, const float* __restrict__ emb,
    const float* __restrict__ wT,
    const float* __restrict__ bih_f, const float* __restrict__ bhh_f,
    const float* __restrict__ bih_b, const float* __restrict__ bhh_b,
    float* __restrict__ xw) {
    int dir = blockIdx.y;
    int t0 = blockIdx.x * 16;
    int tid = threadIdx.x;
    __shared__ __align__(16) float xs[16][256];
    for (int i = 0; i < 16; ++i) {
        int t = t0 + i;
        int pos = dir ? (S_LEN - 1 - t) : t;
        int idx = sent[pos];
        xs[i][tid] = emb[(size_t)idx * 256 + tid];
    }
    __syncthreads();
    const float* w = wT + (size_t)dir * 256 * 1024;
    const float* bi = dir ? bih_b : bih_f;
    const float* bh = dir ? bhh_b : bhh_f;
    float4 bv;
    bv.x = bi[4 * tid + 0] + bh[4 * tid + 0];
    bv.y = bi[4 * tid + 1] + bh[4 * tid + 1];
    bv.z = bi[4 * tid + 2] + bh[4 * tid + 2];
    bv.w = bi[4 * tid + 3] + bh[4 * tid + 3];
    float4 acc[16];
#pragma unroll
    for (int i = 0; i < 16; ++i) acc[i] = bv;
    for (int k4 = 0; k4 < 64; ++k4) {
        float4 w0 = ((const float4*)(w + (size_t)(4 * k4 + 0) * 1024))[tid];
        float4 w1 = ((const float4*)(w + (size_t)(4 * k4 + 1) * 1024))[tid];
        float4 w2 = ((const float4*)(w + (size_t)(4 * k4 + 2) * 1024))[tid];
        float4 w3 = ((const float4*)(w + (size_t)(4 * k4 + 3) * 1024))[tid];
#pragma unroll
        for (int i = 0; i < 16; ++i) {
            float4 xv = *(const float4*)&xs[i][4 * k4];
            acc[i].x = fmaf(w0.x, xv.x, acc[i].x);
            acc[i].y = fmaf(w0.y, xv.x, acc[i].y);
            acc[i].z = fmaf(w0.z, xv.x, acc[i].z);
            acc[i].w = fmaf(w0.w, xv.x, acc[i].w);
            acc[i].x = fmaf(w1.x, xv.y, acc[i].x);
            acc[i].y = fmaf(w1.y, xv.y, acc[i].y);
            acc[i].z = fmaf(w1.z, xv.y, acc[i].z);
            acc[i].w = fmaf(w1.w, xv.y, acc[i].w);
            acc[i].x = fmaf(w2.x, xv.z, acc[i].x);
            acc[i].y = fmaf(w2.y, xv.z, acc[i].y);
            acc[i].z = fmaf(w2.z, xv.z, acc[i].z);
            acc[i].w = fmaf(w2.w, xv.z, acc[i].w);
            acc[i].x = fmaf(w3.x, xv.w, acc[i].x);
            acc[i].y = fmaf(w3.y, xv.w, acc[i].y);
            acc[i].z = fmaf(w3.z, xv.w, acc[i].z);
            acc[i].w = fmaf(w3.w, xv.w, acc[i].w);
        }
    }
#pragma unroll
    for (int i = 0; i < 16; ++i)
        ((float4*)(xw + ((size_t)dir * S_LEN + t0 + i) * 1024))[tid] = acc[i];
}

// ---------------- LSTM recurrence ----------------
// 8 blocks x 256 threads. Block = (dir = blk>>2, wg = blk&3). WG owns h-dims
// [64*wg, 64*wg+64): rows gate*256 + 64*wg + (tid&63). Each thread keeps its
// full 256-float Whh row in VGPRs (launch_bounds(256,1): <=512 VGPR ok).
// Cross-WG h exchange: agent-scope atomics via Infinity Cache + per-step
// arrive counter (release add / acquire spin).
__global__ __launch_bounds__(256, 1) void lstm_rec(
    const float* __restrict__ whh_f, const float* __restrict__ whh_b,
    const float* __restrict__ xw, float* __restrict__ hs,
    int* __restrict__ cnt) {
    int blk = blockIdx.x;
    int dir = blk >> 2;
    int wg = blk & 3;
    int tid = threadIdx.x;
    int gate = tid >> 6;
    int dp = tid & 63;
    int row = gate * 256 + wg * 64 + dp;

    const float* whh = dir ? whh_b : whh_f;
    const float4* wrow = (const float4*)(whh + (size_t)row * 256);
    float4 w[64];
#pragma unroll
    for (int i = 0; i < 64; ++i) w[i] = wrow[i];

    const float* xwd = xw + (size_t)dir * S_LEN * 1024 + row;
    float* hsd = hs + (size_t)dir * S_LEN * 256;
    int* cntd = cnt + dir * S_LEN;

    __shared__ __align__(16) float4 hb[64];   // h_{t-1}, all 256 dims
    __shared__ float zbuf[4][64];
    if (tid < 64) hb[tid] = make_float4(0.f, 0.f, 0.f, 0.f);
    float c = 0.f;
    float xw_cur = xwd[0];
    __syncthreads();

    for (int t = 0; t < S_LEN; ++t) {
        // prefetch next step's xw early (hidden under this step's sync)
        float xw_next = (t + 1 < S_LEN) ? xwd[(size_t)(t + 1) * 1024] : 0.f;
        // matvec: z_row = xw + Whh[row,:] @ h_{t-1}
        float4 a = make_float4(0.f, 0.f, 0.f, 0.f);
#pragma unroll
        for (int i = 0; i < 64; ++i) {
            float4 h4 = hb[i];
            a.x = fmaf(w[i].x, h4.x, a.x);
            a.y = fmaf(w[i].y, h4.y, a.y);
            a.z = fmaf(w[i].z, h4.z, a.z);
            a.w = fmaf(w[i].w, h4.w, a.w);
        }
        float z = xw_cur + ((a.x + a.y) + (a.z + a.w));
        xw_cur = xw_next;
        zbuf[gate][dp] = z;
        __syncthreads();
        if (tid < 64) {
            float zi = zbuf[0][tid], zf = zbuf[1][tid];
            float zg = zbuf[2][tid], zo = zbuf[3][tid];
            float ig = 1.f / (1.f + expf(-zi));
            float fg = 1.f / (1.f + expf(-zf));
            float gg = tanhf(zg);
            float og = 1.f / (1.f + expf(-zo));
            c = fmaf(fg, c, ig * gg);
            float h = og * tanhf(c);
            // straight-to-IC store (agent scope): no local-L2 dirty state
            __hip_atomic_store(&hsd[(size_t)t * 256 + wg * 64 + tid], h,
                               __ATOMIC_RELAXED, __HIP_MEMORY_SCOPE_AGENT);
        }
        __syncthreads();   // vmcnt drain: h stores complete before arrive
        if (tid == 0) {
            __hip_atomic_fetch_add(&cntd[t], 1, __ATOMIC_RELEASE,
                                   __HIP_MEMORY_SCOPE_AGENT);
            while (__hip_atomic_load(&cntd[t], __ATOMIC_RELAXED,
                                     __HIP_MEMORY_SCOPE_AGENT) < 4)
                __builtin_amdgcn_s_sleep(1);
            (void)__hip_atomic_load(&cntd[t], __ATOMIC_ACQUIRE,
                                    __HIP_MEMORY_SCOPE_AGENT);
        }
        __syncthreads();
        if (tid < 64) {
            const float* hrow = hsd + (size_t)t * 256 + 4 * tid;
            float h0 = __hip_atomic_load(hrow + 0, __ATOMIC_RELAXED, __HIP_MEMORY_SCOPE_AGENT);
            float h1 = __hip_atomic_load(hrow + 1, __ATOMIC_RELAXED, __HIP_MEMORY_SCOPE_AGENT);
            float h2 = __hip_atomic_load(hrow + 2, __ATOMIC_RELAXED, __HIP_MEMORY_SCOPE_AGENT);
            float h3 = __hip_atomic_load(hrow + 3, __ATOMIC_RELAXED, __HIP_MEMORY_SCOPE_AGENT);
            hb[tid] = make_float4(h0, h1, h2, h3);
        }
        __syncthreads();
    }
}

// ---------------- feats = [h_f, h_b] @ W_out^T + b_out ----------------
// grid (S, 10), block 64 (one wave): strided dot over 512 + shuffle reduce.
__global__ __launch_bounds__(64) void feats_k(const float* __restrict__ hs,
                                              const float* __restrict__ wout,
                                              const float* __restrict__ bout,
                                              float* __restrict__ feats) {
    int t = blockIdx.x, tau = blockIdx.y, lane = threadIdx.x;
    const float* hf = hs + (size_t)t * 256;
    const float* hbk = hs + (size_t)S_LEN * 256 + (size_t)(S_LEN - 1 - t) * 256;
    const float* w = wout + (size_t)tau * 512;
    float s = 0.f;
#pragma unroll
    for (int m = 0; m < 4; ++m) s = fmaf(w[lane + 64 * m], hf[lane + 64 * m], s);
#pragma unroll
    for (int m = 0; m < 4; ++m) s = fmaf(w[256 + lane + 64 * m], hbk[lane + 64 * m], s);
#pragma unroll
    for (int off = 32; off > 0; off >>= 1) s += __shfl_down(s, off, 64);
    if (lane == 0) feats[(size_t)t * NTAG + tau] = s + bout[tau];
}

// ---------------- Viterbi (single wave; bp table + path in LDS) ----------------
__global__ __launch_bounds__(64) void viterbi_k(const float* __restrict__ feats,
                                                const float* __restrict__ trans,
                                                float* __restrict__ out) {
    __shared__ float fstage[128 * NTAG];          // 5 KB
    __shared__ unsigned char bp[S_LEN * NTAG];    // 40 KB
    __shared__ float path[S_LEN];                 // 16 KB
    __shared__ float fvbuf[NTAG];
    __shared__ float term[NTAG];
    int tid = threadIdx.x;
    float tr[NTAG];
    float trstop = 0.f;
    if (tid < NTAG) {
#pragma unroll
        for (int j = 0; j < NTAG; ++j) tr[j] = trans[tid * NTAG + j];
        trstop = trans[STOP_TAG * NTAG + tid];
    }
    float fv = (tid == START_TAG) ? 0.f : NEGV;
    for (int t0 = 0; t0 < S_LEN; t0 += 128) {
        __syncthreads();
        for (int i = tid; i < 128 * NTAG; i += 64) fstage[i] = feats[(size_t)t0 * NTAG + i];
        __syncthreads();
        for (int tt = 0; tt < 128; ++tt) {
            int t = t0 + tt;
            if (tid < NTAG) fvbuf[tid] = fv;
            __syncthreads();
            if (tid < NTAG) {
                float best = -3.4e38f; int bj = 0;
#pragma unroll
                for (int j = 0; j < NTAG; ++j) {
                    float v = fvbuf[j] + tr[j];
                    if (v > best) { best = v; bj = j; }   // strict > = first max (jnp.argmax)
                }
                bp[t * NTAG + tid] = (unsigned char)bj;
                fv = best + fstage[tt * NTAG + tid];
            }
            __syncthreads();
        }
    }
    if (tid < NTAG) term[tid] = fv + trstop;
    __syncthreads();
    if (tid == 0) {
        float best = -3.4e38f; int bi = 0;
#pragma unroll
        for (int i = 0; i < NTAG; ++i) {
            float v = term[i];
            if (v > best) { best = v; bi = i; }
        }
        out[0] = best;
        int tag = bi;
        for (int t = S_LEN - 1; t >= 0; --t) {
            path[t] = (float)tag;
            tag = bp[t * NTAG + tag];
        }
    }
    __syncthreads();
    for (int i = tid; i < S_LEN; i += 64) out[1 + i] = path[i];
}

extern "C" void kernel_launch(void* const* d_in, const int* in_sizes, int n_in,
                              void* d_out, int out_size, void* d_ws, size_t ws_size,
                              hipStream_t stream) {
    const int* sent = (const int*)d_in[0];
    const float* emb = (const float*)d_in[1];
    const float* wih_f = (const float*)d_in[2];
    const float* whh_f = (const float*)d_in[3];
    const float* bih_f = (const float*)d_in[4];
    const float* bhh_f = (const float*)d_in[5];
    const float* wih_b = (const float*)d_in[6];
    const float* whh_b = (const float*)d_in[7];
    const float* bih_b = (const float*)d_in[8];
    const float* bhh_b = (const float*)d_in[9];
    const float* wout = (const float*)d_in[10];
    const float* bout = (const float*)d_in[11];
    const float* trans = (const float*)d_in[12];

    float* ws = (float*)d_ws;
    float* xw = ws + XW_OFF;
    float* hs = ws + HS_OFF;
    float* wT = ws + WT_OFF;
    float* fe = ws + FE_OFF;
    int* cnt = (int*)(ws + CNT_OFF);

    hipMemsetAsync(cnt, 0, CNT_SZ * sizeof(int), stream);
    hipLaunchKernelGGL(transpose_wih, dim3(8, 32, 2), dim3(32, 32), 0, stream,
                       wih_f, wih_b, wT);
    hipLaunchKernelGGL(xw_gemm, dim3(S_LEN / 16, 2), dim3(256), 0, stream,
                       sent, emb, wT, bih_f, bhh_f, bih_b, bhh_b, xw);
    hipLaunchKernelGGL(lstm_rec, dim3(8), dim3(256), 0, stream,
                       whh_f, whh_b, xw, hs, cnt);
    hipLaunchKernelGGL(feats_k, dim3(S_LEN, NTAG), dim3(64), 0, stream,
                       hs, wout, bout, fe);
    hipLaunchKernelGGL(viterbi_k, dim3(1), dim3(64), 0, stream,
                       fe, trans, (float*)d_out);
}

// Round 2
// 14367.635 us; speedup vs baseline: 1.0491x; 1.0491x over previous
//
#include <hip/hip_runtime.h>
#include <math.h>

#define S_LEN 4096
#define HDIRC 256
#define NTAG 10
#define START_TAG 8
#define STOP_TAG 9
#define NEGV -10000.0f

// -------- workspace layout (float units) --------
#define XW_OFF 0UL
#define XW_SZ  (2UL * S_LEN * 1024)          // xw[dir][t][1024]
#define HS_OFF (XW_OFF + XW_SZ)
#define HS_SZ  (2UL * S_LEN * 256)           // hs[dir][t][256] (dir1 indexed by backward step)
#define WT_OFF (HS_OFF + HS_SZ)
#define WT_SZ  (2UL * 256 * 1024)            // WihT[dir][k][r]
#define FE_OFF (WT_OFF + WT_SZ)
#define FE_SZ  ((size_t)S_LEN * NTAG)        // feats[t][tag]
#define RING_OFF (FE_OFF + FE_SZ + (FE_SZ & 1))  // 8B-aligned
#define RING_SZ (2UL * 2 * 256 * 2)          // u64 ring[dir][slot][dim], as floats

// ---------------- Wih transpose: [1024][256] -> [256][1024] ----------------
__global__ void transpose_wih(const float* __restrict__ wf,
                              const float* __restrict__ wb,
                              float* __restrict__ wT) {
    __shared__ float tile[32][33];
    const float* src = blockIdx.z ? wb : wf;
    float* dst = wT + (size_t)blockIdx.z * 256 * 1024;
    int x = blockIdx.x * 32 + threadIdx.x;   // k  (0..255)
    int y = blockIdx.y * 32 + threadIdx.y;   // r  (0..1023)
    tile[threadIdx.y][threadIdx.x] = src[y * 256 + x];
    __syncthreads();
    int ko = blockIdx.x * 32 + threadIdx.y;
    int ro = blockIdx.y * 32 + threadIdx.x;
    dst[(size_t)ko * 1024 + ro] = tile[threadIdx.x][threadIdx.y];
}

// ---------------- xW = emb[sent] @ Wih^T + (bih+bhh) ----------------
__global__ __launch_bounds__(256) void xw_gemm(
    const int* __restrict__ sent, const float* __restrict__ emb,
    const float* __restrict__ wT,
    const float* __restrict__ bih_f, const float* __restrict__ bhh_f,
    const float* __restrict__ bih_b, const float* __restrict__ bhh_b,
    float* __restrict__ xw) {
    int dir = blockIdx.y;
    int t0 = blockIdx.x * 16;
    int tid = threadIdx.x;
    __shared__ __align__(16) float xs[16][256];
    for (int i = 0; i < 16; ++i) {
        int t = t0 + i;
        int pos = dir ? (S_LEN - 1 - t) : t;
        int idx = sent[pos];
        xs[i][tid] = emb[(size_t)idx * 256 + tid];
    }
    __syncthreads();
    const float* w = wT + (size_t)dir * 256 * 1024;
    const float* bi = dir ? bih_b : bih_f;
    const float* bh = dir ? bhh_b : bhh_f;
    float4 bv;
    bv.x = bi[4 * tid + 0] + bh[4 * tid + 0];
    bv.y = bi[4 * tid + 1] + bh[4 * tid + 1];
    bv.z = bi[4 * tid + 2] + bh[4 * tid + 2];
    bv.w = bi[4 * tid + 3] + bh[4 * tid + 3];
    float4 acc[16];
#pragma unroll
    for (int i = 0; i < 16; ++i) acc[i] = bv;
    for (int k4 = 0; k4 < 64; ++k4) {
        float4 w0 = ((const float4*)(w + (size_t)(4 * k4 + 0) * 1024))[tid];
        float4 w1 = ((const float4*)(w + (size_t)(4 * k4 + 1) * 1024))[tid];
        float4 w2 = ((const float4*)(w + (size_t)(4 * k4 + 2) * 1024))[tid];
        float4 w3 = ((const float4*)(w + (size_t)(4 * k4 + 3) * 1024))[tid];
#pragma unroll
        for (int i = 0; i < 16; ++i) {
            float4 xv = *(const float4*)&xs[i][4 * k4];
            acc[i].x = fmaf(w0.x, xv.x, acc[i].x);
            acc[i].y = fmaf(w0.y, xv.x, acc[i].y);
            acc[i].z = fmaf(w0.z, xv.x, acc[i].z);
            acc[i].w = fmaf(w0.w, xv.x, acc[i].w);
            acc[i].x = fmaf(w1.x, xv.y, acc[i].x);
            acc[i].y = fmaf(w1.y, xv.y, acc[i].y);
            acc[i].z = fmaf(w1.z, xv.y, acc[i].z);
            acc[i].w = fmaf(w1.w, xv.y, acc[i].w);
            acc[i].x = fmaf(w2.x, xv.z, acc[i].x);
            acc[i].y = fmaf(w2.y, xv.z, acc[i].y);
            acc[i].z = fmaf(w2.z, xv.z, acc[i].z);
            acc[i].w = fmaf(w2.w, xv.z, acc[i].w);
            acc[i].x = fmaf(w3.x, xv.w, acc[i].x);
            acc[i].y = fmaf(w3.y, xv.w, acc[i].y);
            acc[i].z = fmaf(w3.z, xv.w, acc[i].z);
            acc[i].w = fmaf(w3.w, xv.w, acc[i].w);
        }
    }
#pragma unroll
    for (int i = 0; i < 16; ++i)
        ((float4*)(xw + ((size_t)dir * S_LEN + t0 + i) * 1024))[tid] = acc[i];
}

// ---------------- LSTM recurrence ----------------
// 8 blocks x 256 threads. Block = (dir = blk>>2, wg = blk&3). WG owns h-dims
// [64*wg, 64*wg+64); thread owns row gate*256 + wg*64 + (tid&63), holds the
// full 256-float Whh row pinned in VGPRs (asm touch defeats re-materialize).
// Cross-WG h exchange: single-copy-atomic 8B {stamp,h} pairs in a 2-deep ring
// through IC; wave0 polls stamps directly (no counter RMW, no second reload).
__global__ __launch_bounds__(256, 1) void lstm_rec(
    const float* __restrict__ whh_f, const float* __restrict__ whh_b,
    const float* __restrict__ xw, float* __restrict__ hs,
    unsigned long long* __restrict__ ring) {
    int blk = blockIdx.x;
    int dir = blk >> 2;
    int wg = blk & 3;
    int tid = threadIdx.x;
    int gate = tid >> 6;
    int dp = tid & 63;
    int row = gate * 256 + wg * 64 + dp;

    const float* whh = dir ? whh_b : whh_f;
    const float4* wrow = (const float4*)(whh + (size_t)row * 256);
    float4 w[64];
#pragma unroll
    for (int i = 0; i < 64; ++i) w[i] = wrow[i];
#pragma unroll
    for (int i = 0; i < 64; ++i)
        asm volatile("" : "+v"(w[i].x), "+v"(w[i].y), "+v"(w[i].z), "+v"(w[i].w));

    const float* xwd = xw + (size_t)dir * S_LEN * 1024 + row;
    float* hsd = hs + (size_t)dir * S_LEN * 256;
    unsigned long long* ringd = ring + dir * 512;   // [slot(2)][dim(256)]

    __shared__ __align__(16) float hbf[256];  // h_{t-1}, all 256 dims
    __shared__ float zbuf[256];               // z for this block's 256 rows
    if (tid < 256) hbf[tid] = 0.f;
    float c = 0.f;
    float xw_cur = xwd[0];
    __syncthreads();

    for (int t = 0; t < S_LEN; ++t) {
        float xw_next = (t + 1 < S_LEN) ? xwd[(size_t)(t + 1) * 1024] : 0.f;
        // z_row = xw + Whh[row,:] @ h_{t-1}; 4 independent FMA chains
        float4 a = make_float4(0.f, 0.f, 0.f, 0.f);
        const float4* hb4 = (const float4*)hbf;
#pragma unroll
        for (int i = 0; i < 64; ++i) {
            float4 h4 = hb4[i];
            a.x = fmaf(w[i].x, h4.x, a.x);
            a.y = fmaf(w[i].y, h4.y, a.y);
            a.z = fmaf(w[i].z, h4.z, a.z);
            a.w = fmaf(w[i].w, h4.w, a.w);
        }
        float z = xw_cur + ((a.x + a.y) + (a.z + a.w));
        xw_cur = xw_next;
        zbuf[tid] = z;            // tid == gate*64 + dp
        __syncthreads();

        unsigned long long* slot = ringd + (size_t)(t & 1) * 256;
        unsigned int want = (unsigned int)(t + 1);
        if (tid < 64) {
            float zi = zbuf[tid], zf = zbuf[64 + tid];
            float zg = zbuf[128 + tid], zo = zbuf[192 + tid];
            float ig = 1.f / (1.f + expf(-zi));
            float fg = 1.f / (1.f + expf(-zf));
            float gg = tanhf(zg);
            float og = 1.f / (1.f + expf(-zo));
            c = fmaf(fg, c, ig * gg);
            float h = og * tanhf(c);
            hsd[(size_t)t * 256 + wg * 64 + tid] = h;   // plain store for feats_k
            unsigned long long pk =
                ((unsigned long long)want << 32) | (unsigned long long)__float_as_uint(h);
            __hip_atomic_store(&slot[wg * 64 + tid], pk,
                               __ATOMIC_RELAXED, __HIP_MEMORY_SCOPE_AGENT);
            // wave0 polls all 256 stamped pairs (4 dims/lane) straight from IC
            unsigned long long v0, v1, v2, v3;
            for (;;) {
                v0 = __hip_atomic_load(&slot[tid], __ATOMIC_RELAXED, __HIP_MEMORY_SCOPE_AGENT);
                v1 = __hip_atomic_load(&slot[tid + 64], __ATOMIC_RELAXED, __HIP_MEMORY_SCOPE_AGENT);
                v2 = __hip_atomic_load(&slot[tid + 128], __ATOMIC_RELAXED, __HIP_MEMORY_SCOPE_AGENT);
                v3 = __hip_atomic_load(&slot[tid + 192], __ATOMIC_RELAXED, __HIP_MEMORY_SCOPE_AGENT);
                bool ok = ((unsigned int)(v0 >> 32) == want) &
                          ((unsigned int)(v1 >> 32) == want) &
                          ((unsigned int)(v2 >> 32) == want) &
                          ((unsigned int)(v3 >> 32) == want);
                if (__all(ok)) break;
            }
            hbf[tid]       = __uint_as_float((unsigned int)v0);
            hbf[tid + 64]  = __uint_as_float((unsigned int)v1);
            hbf[tid + 128] = __uint_as_float((unsigned int)v2);
            hbf[tid + 192] = __uint_as_float((unsigned int)v3);
        }
        __syncthreads();
    }
}

// ---------------- feats = [h_f, h_b] @ W_out^T + b_out ----------------
__global__ __launch_bounds__(64) void feats_k(const float* __restrict__ hs,
                                              const float* __restrict__ wout,
                                              const float* __restrict__ bout,
                                              float* __restrict__ feats) {
    int t = blockIdx.x, tau = blockIdx.y, lane = threadIdx.x;
    const float* hf = hs + (size_t)t * 256;
    const float* hbk = hs + (size_t)S_LEN * 256 + (size_t)(S_LEN - 1 - t) * 256;
    const float* w = wout + (size_t)tau * 512;
    float s = 0.f;
#pragma unroll
    for (int m = 0; m < 4; ++m) s = fmaf(w[lane + 64 * m], hf[lane + 64 * m], s);
#pragma unroll
    for (int m = 0; m < 4; ++m) s = fmaf(w[256 + lane + 64 * m], hbk[lane + 64 * m], s);
#pragma unroll
    for (int off = 32; off > 0; off >>= 1) s += __shfl_down(s, off, 64);
    if (lane == 0) feats[(size_t)t * NTAG + tau] = s + bout[tau];
}

// ---------------- Viterbi (single wave; bp table + path in LDS) ----------------
__global__ __launch_bounds__(64) void viterbi_k(const float* __restrict__ feats,
                                                const float* __restrict__ trans,
                                                float* __restrict__ out) {
    __shared__ float fstage[128 * NTAG];
    __shared__ unsigned char bp[S_LEN * NTAG];
    __shared__ float path[S_LEN];
    __shared__ float fvbuf[NTAG];
    __shared__ float term[NTAG];
    int tid = threadIdx.x;
    float tr[NTAG];
    float trstop = 0.f;
    if (tid < NTAG) {
#pragma unroll
        for (int j = 0; j < NTAG; ++j) tr[j] = trans[tid * NTAG + j];
        trstop = trans[STOP_TAG * NTAG + tid];
    }
    float fv = (tid == START_TAG) ? 0.f : NEGV;
    for (int t0 = 0; t0 < S_LEN; t0 += 128) {
        __syncthreads();
        for (int i = tid; i < 128 * NTAG; i += 64) fstage[i] = feats[(size_t)t0 * NTAG + i];
        __syncthreads();
        for (int tt = 0; tt < 128; ++tt) {
            int t = t0 + tt;
            if (tid < NTAG) fvbuf[tid] = fv;
            __syncthreads();
            if (tid < NTAG) {
                float best = -3.4e38f; int bj = 0;
#pragma unroll
                for (int j = 0; j < NTAG; ++j) {
                    float v = fvbuf[j] + tr[j];
                    if (v > best) { best = v; bj = j; }
                }
                bp[t * NTAG + tid] = (unsigned char)bj;
                fv = best + fstage[tt * NTAG + tid];
            }
            __syncthreads();
        }
    }
    if (tid < NTAG) term[tid] = fv + trstop;
    __syncthreads();
    if (tid == 0) {
        float best = -3.4e38f; int bi = 0;
#pragma unroll
        for (int i = 0; i < NTAG; ++i) {
            float v = term[i];
            if (v > best) { best = v; bi = i; }
        }
        out[0] = best;
        int tag = bi;
        for (int t = S_LEN - 1; t >= 0; --t) {
            path[t] = (float)tag;
            tag = bp[t * NTAG + tag];
        }
    }
    __syncthreads();
    for (int i = tid; i < S_LEN; i += 64) out[1 + i] = path[i];
}

extern "C" void kernel_launch(void* const* d_in, const int* in_sizes, int n_in,
                              void* d_out, int out_size, void* d_ws, size_t ws_size,
                              hipStream_t stream) {
    const int* sent = (const int*)d_in[0];
    const float* emb = (const float*)d_in[1];
    const float* wih_f = (const float*)d_in[2];
    const float* whh_f = (const float*)d_in[3];
    const float* bih_f = (const float*)d_in[4];
    const float* bhh_f = (const float*)d_in[5];
    const float* wih_b = (const float*)d_in[6];
    const float* whh_b = (const float*)d_in[7];
    const float* bih_b = (const float*)d_in[8];
    const float* bhh_b = (const float*)d_in[9];
    const float* wout = (const float*)d_in[10];
    const float* bout = (const float*)d_in[11];
    const float* trans = (const float*)d_in[12];

    float* ws = (float*)d_ws;
    float* xw = ws + XW_OFF;
    float* hs = ws + HS_OFF;
    float* wT = ws + WT_OFF;
    float* fe = ws + FE_OFF;
    unsigned long long* ring = (unsigned long long*)(ws + RING_OFF);

    hipLaunchKernelGGL(transpose_wih, dim3(8, 32, 2), dim3(32, 32), 0, stream,
                       wih_f, wih_b, wT);
    hipLaunchKernelGGL(xw_gemm, dim3(S_LEN / 16, 2), dim3(256), 0, stream,
                       sent, emb, wT, bih_f, bhh_f, bih_b, bhh_b, xw);
    hipLaunchKernelGGL(lstm_rec, dim3(8), dim3(256), 0, stream,
                       whh_f, whh_b, xw, hs, ring);
    hipLaunchKernelGGL(feats_k, dim3(S_LEN, NTAG), dim3(64), 0, stream,
                       hs, wout, bout, fe);
    hipLaunchKernelGGL(viterbi_k, dim3(1), dim3(64), 0, stream,
                       fe, trans, (float*)d_out);
}